// Round 12
// baseline (496.829 us; speedup 1.0000x reference)
//
#include <hip/hip_runtime.h>
#include <hip/hip_bf16.h>

#define B_   64
#define CIN  256
#define COUT 512
#define S_   4096
#define HID  64
#define KEXP 4

typedef float f32x4 __attribute__((ext_vector_type(4)));
typedef short bf16x8 __attribute__((ext_vector_type(8)));

static __device__ __forceinline__ unsigned short f2bf(float f) {
    union { float f; unsigned u; } c; c.f = f;
    unsigned r = c.u + 0x7FFFu + ((c.u >> 16) & 1u);
    return (unsigned short)(r >> 16);
}
static __device__ __forceinline__ float bf2f(unsigned short u) {
    union { unsigned u; float f; } c; c.u = ((unsigned)u) << 16;
    return c.f;
}

// ---------------- K_GRAM_PART: partial Gram (bf16) + partial pooled + xF (frag-packed bf16) ----
#define GSTR 68   // shorts per LDS row (136B)
__global__ __launch_bounds__(512, 2) void k_gram_part(const float* __restrict__ x,
                                                      unsigned short* __restrict__ part,
                                                      float* __restrict__ ppart,
                                                      unsigned short* __restrict__ xF) {
    __shared__ unsigned short lds[256 * GSTR];   // 34816 B
    int bid = blockIdx.x;
    int b = bid & 63, sc = bid >> 6;
    int t = threadIdx.x, lane = t & 63, wv = t >> 6;
    int wr = wv >> 1, wc = wv & 1;               // wave tile: rows wr*64.., cols wc*128..
    const float* xb = x + (size_t)b * CIN * S_;
    unsigned short* xFb = xF + (size_t)b * S_ * CIN;

    f32x4 acc[4][8] = {};
    float psum[8] = {0.f, 0.f, 0.f, 0.f, 0.f, 0.f, 0.f, 0.f};

    for (int step = 0; step < 16; ++step) {
        int s0 = sc * 1024 + step * 64;
        __syncthreads();
#pragma unroll
        for (int p = 0; p < 8; ++p) {
            int i = t + p * 512;
            int row = i >> 4, f4 = i & 15;
            float4 v = *(const float4*)(xb + (size_t)row * S_ + s0 + f4 * 4);
            psum[p] += v.x + v.y + v.z + v.w;
            unsigned short u[4] = {f2bf(v.x), f2bf(v.y), f2bf(v.z), f2bf(v.w)};
            *(uint2*)&lds[row * GSTR + f4 * 4] = *(const uint2*)u;
        }
        __syncthreads();
        // ---- xF write: frag-packed, 1KB-contiguous per wave-chunk ----
        {
#pragma unroll
            for (int it = 0; it < 4; ++it) {
                int slot = t + it * 512;
                int chunk = slot >> 6;           // 0..31 = st_l*8 + kb
                int st_l = chunk >> 3, kb = chunk & 7;
                int l = slot & 63;
                unsigned short tmp[8];
#pragma unroll
                for (int j = 0; j < 8; ++j)
                    tmp[j] = lds[(kb * 32 + (l >> 4) * 8 + j) * GSTR + st_l * 16 + (l & 15)];
                *(uint4*)(xFb + ((size_t)((s0 >> 4) + st_l) * 8 + kb) * 512 + l * 8) = *(const uint4*)tmp;
            }
        }
        // ---- Gram MFMA ----
#pragma unroll
        for (int kk = 0; kk < 2; ++kk) {
            bf16x8 bfr[8];
#pragma unroll
            for (int nf = 0; nf < 8; ++nf)
                bfr[nf] = *(const bf16x8*)&lds[(wc * 128 + nf * 16 + (lane & 15)) * GSTR + kk * 32 + (lane >> 4) * 8];
#pragma unroll
            for (int mfi = 0; mfi < 4; ++mfi) {
                bf16x8 afr = *(const bf16x8*)&lds[(wr * 64 + mfi * 16 + (lane & 15)) * GSTR + kk * 32 + (lane >> 4) * 8];
#pragma unroll
                for (int nf = 0; nf < 8; ++nf)
                    acc[mfi][nf] = __builtin_amdgcn_mfma_f32_16x16x32_bf16(afr, bfr[nf], acc[mfi][nf], 0, 0, 0);
            }
        }
    }
#pragma unroll
    for (int p = 0; p < 8; ++p) {
        float s = psum[p];
        s += __shfl_xor(s, 1); s += __shfl_xor(s, 2);
        s += __shfl_xor(s, 4); s += __shfl_xor(s, 8);
        if ((t & 15) == 0) ppart[((size_t)sc * 64 + b) * 256 + ((t + p * 512) >> 4)] = s;
    }
    unsigned short* pb = part + ((size_t)sc * 64 + b) * 65536;
#pragma unroll
    for (int mfi = 0; mfi < 4; ++mfi) {
#pragma unroll
        for (int r = 0; r < 4; ++r) {
            int row = wr * 64 + mfi * 16 + (lane >> 4) * 4 + r;
#pragma unroll
            for (int nf = 0; nf < 8; ++nf)
                pb[row * 256 + wc * 128 + nf * 16 + (lane & 15)] = f2bf(acc[mfi][nf][r]);
        }
    }
}

// ---------------- K_GRED: reduce 4 bf16 partials -> ghat bf16, pooled ----------------
__global__ __launch_bounds__(256) void k_gred(const unsigned short* __restrict__ part,
                                              const float* __restrict__ ppart,
                                              unsigned short* __restrict__ ghat,
                                              float* __restrict__ pooled) {
    int b = blockIdx.x, t = threadIdx.x;
    const size_t bo = (size_t)b * 65536;
    const size_t scs = (size_t)64 * 65536;
    const float inv = 1.f / S_;
    for (int it = 0; it < 32; ++it) {
        size_t i = bo + (size_t)(it * 256 + t) * 8;
        union { uint4 v; unsigned short s[8]; } a0, a1, a2, a3, o;
        a0.v = *(const uint4*)(part + i);
        a1.v = *(const uint4*)(part + scs + i);
        a2.v = *(const uint4*)(part + 2 * scs + i);
        a3.v = *(const uint4*)(part + 3 * scs + i);
#pragma unroll
        for (int j = 0; j < 8; ++j)
            o.s[j] = f2bf((bf2f(a0.s[j]) + bf2f(a1.s[j]) + bf2f(a2.s[j]) + bf2f(a3.s[j])) * inv);
        *(uint4*)&ghat[i] = o.v;
    }
    float p = ppart[(size_t)b * 256 + t] + ppart[(size_t)(64 + b) * 256 + t]
            + ppart[(size_t)(128 + b) * 256 + t] + ppart[(size_t)(192 + b) * 256 + t];
    pooled[b * 256 + t] = p * inv;
}

// ---------------- K2: attention weights ----------------
__global__ __launch_bounds__(64) void k_att(const float* __restrict__ pooled,
                                            const float* __restrict__ w1,
                                            const float* __restrict__ w2,
                                            const float* __restrict__ b2,
                                            float* __restrict__ att_out) {
    int b = blockIdx.x, t = threadIdx.x;
    __shared__ float pl[CIN];
    __shared__ float hl[HID];
    __shared__ float satt[KEXP];
    for (int j = t; j < CIN; j += 64) pl[j] = pooled[b * CIN + j];
    __syncthreads();
    float acc = 0.f;
    const float* w1r = w1 + t * CIN;
#pragma unroll 4
    for (int c = 0; c < CIN; c += 4) {
        float4 w = *(const float4*)(w1r + c);
        acc += w.x * pl[c] + w.y * pl[c + 1] + w.z * pl[c + 2] + w.w * pl[c + 3];
    }
    hl[t] = fmaxf(acc, 0.f);
    __syncthreads();
    if (t < KEXP) {
        float a = 0.f;
        for (int j = 0; j < HID; ++j) a += hl[j] * w2[t * HID + j];
        satt[t] = (a + b2[t]) * (1.0f / 30.0f);
    }
    __syncthreads();
    if (t == 0) {
        float m = fmaxf(fmaxf(satt[0], satt[1]), fmaxf(satt[2], satt[3]));
        float e0 = expf(satt[0] - m), e1 = expf(satt[1] - m);
        float e2 = expf(satt[2] - m), e3 = expf(satt[3] - m);
        float inv = 1.f / (e0 + e1 + e2 + e3);
        att_out[b * KEXP + 0] = e0 * inv;
        att_out[b * KEXP + 1] = e1 * inv;
        att_out[b * KEXP + 2] = e2 * inv;
        att_out[b * KEXP + 3] = e3 * inv;
    }
}

// ---------------- K2b: Wb[b] = sum_k att[b,k] conv_w[k]  (bf16 to ws) ----------------
__global__ __launch_bounds__(256) void k_wb(const float* __restrict__ conv_w,
                                            const float* __restrict__ att,
                                            unsigned short* __restrict__ wb) {
    int bid = blockIdx.x;
    int b = bid >> 5, o0 = (bid & 31) * 16;
    int t = threadIdx.x;
    int o = o0 + (t >> 4);
    int i0 = (t & 15) * 16;
    float ak[KEXP];
#pragma unroll
    for (int k = 0; k < KEXP; ++k) ak[k] = att[b * KEXP + k];
    float acc[16];
#pragma unroll
    for (int j = 0; j < 16; ++j) acc[j] = 0.f;
#pragma unroll
    for (int k = 0; k < KEXP; ++k) {
        const float* src = conv_w + ((size_t)(k * COUT + o)) * CIN + i0;
#pragma unroll
        for (int j4 = 0; j4 < 4; ++j4) {
            float4 v = *(const float4*)(src + j4 * 4);
            acc[j4 * 4 + 0] += ak[k] * v.x;
            acc[j4 * 4 + 1] += ak[k] * v.y;
            acc[j4 * 4 + 2] += ak[k] * v.z;
            acc[j4 * 4 + 3] += ak[k] * v.w;
        }
    }
    unsigned short us[16];
#pragma unroll
    for (int j = 0; j < 16; ++j) us[j] = f2bf(acc[j]);
    unsigned short* dst = wb + (size_t)(b * COUT + o) * CIN + i0;
    *(uint4*)(dst) = *(const uint4*)(us);
    *(uint4*)(dst + 8) = *(const uint4*)(us + 8);
}

#define ASTR 264

// ---------------- K_Z: Z[b] = Wb[b] @ Ghat[b] ----------------
__global__ __launch_bounds__(256, 2) void k_z(const unsigned short* __restrict__ wb,
                                              const unsigned short* __restrict__ ghat,
                                              float* __restrict__ zout) {
    __shared__ unsigned short lds_a[128 * ASTR];
    int bid = blockIdx.x;
    int b = bid & 63;
    int tile = bid >> 6;               // 0..7
    int m0 = (tile & 3) * 128, n0 = (tile >> 2) * 128;
    int t = threadIdx.x;
    {
        int row = t >> 1, half = t & 1;
        const unsigned short* src = wb + (size_t)(b * COUT + m0 + row) * CIN + half * 128;
        unsigned short* dstrow = &lds_a[row * ASTR + half * 128];
#pragma unroll
        for (int j = 0; j < 16; ++j)
            *(uint4*)(dstrow + j * 8) = *(const uint4*)(src + j * 8);
    }
    __syncthreads();

    int lane = t & 63;
    int wid = t >> 6;
    int arow = lane & 15;
    int kq = lane >> 4;
    int col0 = n0 + wid * 32 + (lane & 15);
    int col1 = col0 + 16;
    const unsigned short* gb = ghat + (size_t)b * 256 * 256;

    f32x4 acc[8][2] = {};
#pragma unroll
    for (int kk = 0; kk < 8; ++kk) {
        bf16x8 b0 = *(const bf16x8*)(gb + (size_t)col0 * 256 + kk * 32 + kq * 8);
        bf16x8 b1 = *(const bf16x8*)(gb + (size_t)col1 * 256 + kk * 32 + kq * 8);
#pragma unroll
        for (int mf = 0; mf < 8; ++mf) {
            int row = mf * 16 + arow;
            bf16x8 a = *(const bf16x8*)&lds_a[row * ASTR + kk * 32 + kq * 8];
            acc[mf][0] = __builtin_amdgcn_mfma_f32_16x16x32_bf16(a, b0, acc[mf][0], 0, 0, 0);
            acc[mf][1] = __builtin_amdgcn_mfma_f32_16x16x32_bf16(a, b1, acc[mf][1], 0, 0, 0);
        }
    }
#pragma unroll
    for (int mf = 0; mf < 8; ++mf) {
#pragma unroll
        for (int r = 0; r < 4; ++r) {
            int row = m0 + mf * 16 + (lane >> 4) * 4 + r;
            size_t rb = ((size_t)b * COUT + row) * 256;
#pragma unroll
            for (int nf = 0; nf < 2; ++nf) {
                int col = n0 + wid * 32 + nf * 16 + (lane & 15);
                zout[rb + col] = acc[mf][nf][r];
            }
        }
    }
}

// ---------------- K_V: mu/rstd per (b,o) ----------------
__global__ __launch_bounds__(256) void k_v(const float* __restrict__ z,
                                           const unsigned short* __restrict__ wb,
                                           const float* __restrict__ pooled,
                                           float* __restrict__ mu,
                                           float* __restrict__ rstd) {
    int gid = blockIdx.x * 4 + (threadIdx.x >> 6);   // b*512 + o
    int lane = threadIdx.x & 63;
    int b = gid >> 9;
    const float* zr = z + (size_t)gid * 256;
    const unsigned short* wr = wb + (size_t)gid * 256;

    float4 zv = *(const float4*)(zr + lane * 4);
    ushort4 wu = *(const ushort4*)(wr + lane * 4);
    float w0 = bf2f(wu.x), w1 = bf2f(wu.y), w2 = bf2f(wu.z), w3 = bf2f(wu.w);
    float4 pv = *(const float4*)(pooled + b * CIN + lane * 4);

    float v = zv.x * w0 + zv.y * w1 + zv.z * w2 + zv.w * w3;
    float m = pv.x * w0 + pv.y * w1 + pv.z * w2 + pv.w * w3;
#pragma unroll
    for (int off = 1; off < 64; off <<= 1) {
        v += __shfl_xor(v, off);
        m += __shfl_xor(m, off);
    }
    if (lane == 0) {
        float var = v - m * m;
        mu[gid] = m;
        rstd[gid] = rsqrtf(var + 1e-5f);
    }
}

static __device__ __forceinline__ float gelu_t(float z) {
    float d = -1.5957691216f * z * (1.f + 0.044715f * z * z);
    return z * __builtin_amdgcn_rcpf(1.f + __expf(d));
}

// ---------------- K_MAIN13: barrier-free, zero-LDS; amplification killed by XCD-L2 sharing ----
// grid = 1024: xcd=bid&7; local=bid>>3: rh=local&3 (fastest -> same-quarter readers
// co-scheduled, L2-hit), sq=(local>>2)&3, bq=local>>4; b=xcd+8*bq (xF writer's XCD).
// 256 thr = 4 waves x 32 rows. A[2][8] in VGPR. B: depth-2 reg ping-pong, 16 cols/step.
// No barriers -> stores are fire-and-forget (write BW drains asynchronously via L2).
static __device__ __forceinline__ void loadB(bf16x8 (&dst)[8], const unsigned short* p) {
#pragma unroll
    for (int kk = 0; kk < 8; ++kk) dst[kk] = *(const bf16x8*)(p + kk * 512);
}

__global__ __launch_bounds__(256) void k_main13(const unsigned short* __restrict__ xF,
                                                const unsigned short* __restrict__ wb,
                                                const float* __restrict__ mu,
                                                const float* __restrict__ rstd,
                                                const float* __restrict__ gamma,
                                                const float* __restrict__ beta,
                                                float* __restrict__ out) {
    int bid = blockIdx.x;
    int xcd = bid & 7;
    int local = bid >> 3;
    int rh = local & 3;
    int sq = (local >> 2) & 3;
    int bq = local >> 4;
    int b = xcd + 8 * bq;

    int t = threadIdx.x, lane = t & 63, w = t >> 6;
    int lm = lane & 15, lk = lane >> 4;
    int row0 = rh * 128 + w * 32;

    // ---- A frags: 32 rows/wave, direct from global (L3/L2-hot) ----
    bf16x8 A[2][8];
    const unsigned short* wbb = wb + (size_t)(b * COUT + row0 + lm) * CIN + lk * 8;
#pragma unroll
    for (int rf = 0; rf < 2; ++rf)
#pragma unroll
        for (int kk = 0; kk < 8; ++kk)
            A[rf][kk] = *(const bf16x8*)(wbb + (size_t)(rf * 16) * CIN + kk * 32);

    float mu_r[8], rs_r[8];
#pragma unroll
    for (int rf = 0; rf < 2; ++rf)
#pragma unroll
        for (int rr = 0; rr < 4; ++rr) {
            int row = b * COUT + row0 + rf * 16 + lk * 4 + rr;
            mu_r[rf * 4 + rr] = mu[row];
            rs_r[rf * 4 + rr] = rstd[row];
        }

    const float* gq = gamma + sq * 1024;
    const float* bq_ = beta + sq * 1024;
    float* outb = out + (size_t)(b * COUT + row0) * S_ + sq * 1024;
    const unsigned short* xFq = xF + (size_t)b * S_ * CIN + (size_t)sq * 262144 + lane * 8;

    bf16x8 B0[8], B1[8];
    loadB(B0, xFq);   // st 0

#define STEP(st_, Bc)                                                                        \
    {                                                                                        \
        f32x4 a0 = {0.f, 0.f, 0.f, 0.f}, a1 = {0.f, 0.f, 0.f, 0.f};                         \
        _Pragma("unroll") for (int kk = 0; kk < 8; ++kk) {                                   \
            a0 = __builtin_amdgcn_mfma_f32_16x16x32_bf16(A[0][kk], Bc[kk], a0, 0, 0, 0);     \
            a1 = __builtin_amdgcn_mfma_f32_16x16x32_bf16(A[1][kk], Bc[kk], a1, 0, 0, 0);     \
        }                                                                                    \
        int cloc = (st_) * 16 + lm;                                                          \
        float g = gq[cloc], be = bq_[cloc];                                                  \
        _Pragma("unroll") for (int rr = 0; rr < 4; ++rr) {                                   \
            float z0 = (a0[rr] - mu_r[rr]) * rs_r[rr] * g + be;                              \
            outb[(size_t)(lk * 4 + rr) * S_ + cloc] = gelu_t(z0);                            \
            float z1 = (a1[rr] - mu_r[4 + rr]) * rs_r[4 + rr] * g + be;                      \
            outb[(size_t)(16 + lk * 4 + rr) * S_ + cloc] = gelu_t(z1);                       \
        }                                                                                    \
    }

    for (int st = 0; st < 64; st += 2) {
        loadB(B1, xFq + (size_t)(st + 1) * 4096);
        STEP(st, B0)
        int nn = (st + 2 < 64) ? st + 2 : 63;
        loadB(B0, xFq + (size_t)nn * 4096);
        STEP(st + 1, B1)
    }
#undef STEP
}

extern "C" void kernel_launch(void* const* d_in, const int* in_sizes, int n_in,
                              void* d_out, int out_size, void* d_ws, size_t ws_size,
                              hipStream_t stream) {
    const float* x      = (const float*)d_in[0];
    const float* w1     = (const float*)d_in[1];
    const float* w2     = (const float*)d_in[2];
    const float* b2     = (const float*)d_in[3];
    const float* conv_w = (const float*)d_in[4];
    // conv_b (d_in[5]) is annihilated by LayerNorm — unused.
    const float* gamma  = (const float*)d_in[6];
    const float* beta   = (const float*)d_in[7];
    float* out = (float*)d_out;

    float* pooled = (float*)d_ws;                                     // 64 KiB
    float* att    = (float*)((char*)d_ws + 65536);                    // 1 KiB
    unsigned short* wb   = (unsigned short*)((char*)d_ws + 262144);   // 16 MiB
    unsigned short* ghat = (unsigned short*)((char*)d_ws + 17039360); // 8 MiB
    float* mu   = (float*)((char*)d_ws + 25427968);                   // 128 KiB
    float* rstd = (float*)((char*)d_ws + 25559040);                   // 128 KiB
    float* ppart = (float*)((char*)d_ws + 25690112);                  // 256 KiB
    // xF: 128 MiB @ 32 MiB (ws_size >= 161.5 MiB proven — xF path ran in R4-R11)
    unsigned short* xF = (unsigned short*)((char*)d_ws + 33554432);

    // scratch inside d_out (537 MB): part (bf16, 33.5 MB) @0, zbuf 33.5 MB @64MB;
    // both dead before k_main13 rewrites d_out
    unsigned short* part = (unsigned short*)out;
    float* zbuf = (float*)((char*)d_out + 67108864);

    k_gram_part<<<256, 512, 0, stream>>>(x, part, ppart, xF);
    k_gred<<<B_, 256, 0, stream>>>(part, ppart, ghat, pooled);
    k_att<<<B_, 64, 0, stream>>>(pooled, w1, w2, b2, att);
    k_wb<<<B_ * 32, 256, 0, stream>>>(conv_w, att, wb);
    k_z<<<512, 256, 0, stream>>>(wb, ghat, zbuf);
    k_v<<<B_ * COUT / 4, 256, 0, stream>>>(zbuf, wb, pooled, mu, rstd);
    k_main13<<<1024, 256, 0, stream>>>(xF, wb, mu, rstd, gamma, beta, out);
}

// Round 13
// 438.148 us; speedup vs baseline: 1.1339x; 1.1339x over previous
//
#include <hip/hip_runtime.h>
#include <hip/hip_bf16.h>

#define B_   64
#define CIN  256
#define COUT 512
#define S_   4096
#define HID  64
#define KEXP 4

typedef float f32x4 __attribute__((ext_vector_type(4)));
typedef short bf16x8 __attribute__((ext_vector_type(8)));

static __device__ __forceinline__ unsigned short f2bf(float f) {
    union { float f; unsigned u; } c; c.f = f;
    unsigned r = c.u + 0x7FFFu + ((c.u >> 16) & 1u);
    return (unsigned short)(r >> 16);
}
static __device__ __forceinline__ float bf2f(unsigned short u) {
    union { unsigned u; float f; } c; c.u = ((unsigned)u) << 16;
    return c.f;
}

// async global->LDS DMA, 16B per lane (HW: lds dest = uniform base + lane*16)
static __device__ __forceinline__ void gl16(const unsigned short* g, unsigned short* l) {
    __builtin_amdgcn_global_load_lds(
        (const __attribute__((address_space(1))) void*)g,
        (__attribute__((address_space(3))) void*)l,
        16, 0, 0);
}

// ---------------- K_GRAM_PART: partial Gram (bf16) + partial pooled + xF (frag-packed bf16) ----
#define GSTR 68   // shorts per LDS row (136B)
__global__ __launch_bounds__(512, 2) void k_gram_part(const float* __restrict__ x,
                                                      unsigned short* __restrict__ part,
                                                      float* __restrict__ ppart,
                                                      unsigned short* __restrict__ xF) {
    __shared__ unsigned short lds[256 * GSTR];   // 34816 B
    int bid = blockIdx.x;
    int b = bid & 63, sc = bid >> 6;
    int t = threadIdx.x, lane = t & 63, wv = t >> 6;
    int wr = wv >> 1, wc = wv & 1;               // wave tile: rows wr*64.., cols wc*128..
    const float* xb = x + (size_t)b * CIN * S_;
    unsigned short* xFb = xF + (size_t)b * S_ * CIN;

    f32x4 acc[4][8] = {};
    float psum[8] = {0.f, 0.f, 0.f, 0.f, 0.f, 0.f, 0.f, 0.f};

    for (int step = 0; step < 16; ++step) {
        int s0 = sc * 1024 + step * 64;
        __syncthreads();
#pragma unroll
        for (int p = 0; p < 8; ++p) {
            int i = t + p * 512;
            int row = i >> 4, f4 = i & 15;
            float4 v = *(const float4*)(xb + (size_t)row * S_ + s0 + f4 * 4);
            psum[p] += v.x + v.y + v.z + v.w;
            unsigned short u[4] = {f2bf(v.x), f2bf(v.y), f2bf(v.z), f2bf(v.w)};
            *(uint2*)&lds[row * GSTR + f4 * 4] = *(const uint2*)u;
        }
        __syncthreads();
        // ---- xF write: frag-packed, 1KB-contiguous per wave-chunk ----
        {
#pragma unroll
            for (int it = 0; it < 4; ++it) {
                int slot = t + it * 512;
                int chunk = slot >> 6;           // 0..31 = st_l*8 + kb
                int st_l = chunk >> 3, kb = chunk & 7;
                int l = slot & 63;
                unsigned short tmp[8];
#pragma unroll
                for (int j = 0; j < 8; ++j)
                    tmp[j] = lds[(kb * 32 + (l >> 4) * 8 + j) * GSTR + st_l * 16 + (l & 15)];
                *(uint4*)(xFb + ((size_t)((s0 >> 4) + st_l) * 8 + kb) * 512 + l * 8) = *(const uint4*)tmp;
            }
        }
        // ---- Gram MFMA ----
#pragma unroll
        for (int kk = 0; kk < 2; ++kk) {
            bf16x8 bfr[8];
#pragma unroll
            for (int nf = 0; nf < 8; ++nf)
                bfr[nf] = *(const bf16x8*)&lds[(wc * 128 + nf * 16 + (lane & 15)) * GSTR + kk * 32 + (lane >> 4) * 8];
#pragma unroll
            for (int mfi = 0; mfi < 4; ++mfi) {
                bf16x8 afr = *(const bf16x8*)&lds[(wr * 64 + mfi * 16 + (lane & 15)) * GSTR + kk * 32 + (lane >> 4) * 8];
#pragma unroll
                for (int nf = 0; nf < 8; ++nf)
                    acc[mfi][nf] = __builtin_amdgcn_mfma_f32_16x16x32_bf16(afr, bfr[nf], acc[mfi][nf], 0, 0, 0);
            }
        }
    }
#pragma unroll
    for (int p = 0; p < 8; ++p) {
        float s = psum[p];
        s += __shfl_xor(s, 1); s += __shfl_xor(s, 2);
        s += __shfl_xor(s, 4); s += __shfl_xor(s, 8);
        if ((t & 15) == 0) ppart[((size_t)sc * 64 + b) * 256 + ((t + p * 512) >> 4)] = s;
    }
    unsigned short* pb = part + ((size_t)sc * 64 + b) * 65536;
#pragma unroll
    for (int mfi = 0; mfi < 4; ++mfi) {
#pragma unroll
        for (int r = 0; r < 4; ++r) {
            int row = wr * 64 + mfi * 16 + (lane >> 4) * 4 + r;
#pragma unroll
            for (int nf = 0; nf < 8; ++nf)
                pb[row * 256 + wc * 128 + nf * 16 + (lane & 15)] = f2bf(acc[mfi][nf][r]);
        }
    }
}

// ---------------- K_GRED: reduce 4 bf16 partials -> ghat bf16, pooled ----------------
__global__ __launch_bounds__(256) void k_gred(const unsigned short* __restrict__ part,
                                              const float* __restrict__ ppart,
                                              unsigned short* __restrict__ ghat,
                                              float* __restrict__ pooled) {
    int b = blockIdx.x, t = threadIdx.x;
    const size_t bo = (size_t)b * 65536;
    const size_t scs = (size_t)64 * 65536;
    const float inv = 1.f / S_;
    for (int it = 0; it < 32; ++it) {
        size_t i = bo + (size_t)(it * 256 + t) * 8;
        union { uint4 v; unsigned short s[8]; } a0, a1, a2, a3, o;
        a0.v = *(const uint4*)(part + i);
        a1.v = *(const uint4*)(part + scs + i);
        a2.v = *(const uint4*)(part + 2 * scs + i);
        a3.v = *(const uint4*)(part + 3 * scs + i);
#pragma unroll
        for (int j = 0; j < 8; ++j)
            o.s[j] = f2bf((bf2f(a0.s[j]) + bf2f(a1.s[j]) + bf2f(a2.s[j]) + bf2f(a3.s[j])) * inv);
        *(uint4*)&ghat[i] = o.v;
    }
    float p = ppart[(size_t)b * 256 + t] + ppart[(size_t)(64 + b) * 256 + t]
            + ppart[(size_t)(128 + b) * 256 + t] + ppart[(size_t)(192 + b) * 256 + t];
    pooled[b * 256 + t] = p * inv;
}

// ---------------- K2: attention weights ----------------
__global__ __launch_bounds__(64) void k_att(const float* __restrict__ pooled,
                                            const float* __restrict__ w1,
                                            const float* __restrict__ w2,
                                            const float* __restrict__ b2,
                                            float* __restrict__ att_out) {
    int b = blockIdx.x, t = threadIdx.x;
    __shared__ float pl[CIN];
    __shared__ float hl[HID];
    __shared__ float satt[KEXP];
    for (int j = t; j < CIN; j += 64) pl[j] = pooled[b * CIN + j];
    __syncthreads();
    float acc = 0.f;
    const float* w1r = w1 + t * CIN;
#pragma unroll 4
    for (int c = 0; c < CIN; c += 4) {
        float4 w = *(const float4*)(w1r + c);
        acc += w.x * pl[c] + w.y * pl[c + 1] + w.z * pl[c + 2] + w.w * pl[c + 3];
    }
    hl[t] = fmaxf(acc, 0.f);
    __syncthreads();
    if (t < KEXP) {
        float a = 0.f;
        for (int j = 0; j < HID; ++j) a += hl[j] * w2[t * HID + j];
        satt[t] = (a + b2[t]) * (1.0f / 30.0f);
    }
    __syncthreads();
    if (t == 0) {
        float m = fmaxf(fmaxf(satt[0], satt[1]), fmaxf(satt[2], satt[3]));
        float e0 = expf(satt[0] - m), e1 = expf(satt[1] - m);
        float e2 = expf(satt[2] - m), e3 = expf(satt[3] - m);
        float inv = 1.f / (e0 + e1 + e2 + e3);
        att_out[b * KEXP + 0] = e0 * inv;
        att_out[b * KEXP + 1] = e1 * inv;
        att_out[b * KEXP + 2] = e2 * inv;
        att_out[b * KEXP + 3] = e3 * inv;
    }
}

// ---------------- K2b: Wb[b] = sum_k att[b,k] conv_w[k]  (bf16 to ws) ----------------
__global__ __launch_bounds__(256) void k_wb(const float* __restrict__ conv_w,
                                            const float* __restrict__ att,
                                            unsigned short* __restrict__ wb) {
    int bid = blockIdx.x;
    int b = bid >> 5, o0 = (bid & 31) * 16;
    int t = threadIdx.x;
    int o = o0 + (t >> 4);
    int i0 = (t & 15) * 16;
    float ak[KEXP];
#pragma unroll
    for (int k = 0; k < KEXP; ++k) ak[k] = att[b * KEXP + k];
    float acc[16];
#pragma unroll
    for (int j = 0; j < 16; ++j) acc[j] = 0.f;
#pragma unroll
    for (int k = 0; k < KEXP; ++k) {
        const float* src = conv_w + ((size_t)(k * COUT + o)) * CIN + i0;
#pragma unroll
        for (int j4 = 0; j4 < 4; ++j4) {
            float4 v = *(const float4*)(src + j4 * 4);
            acc[j4 * 4 + 0] += ak[k] * v.x;
            acc[j4 * 4 + 1] += ak[k] * v.y;
            acc[j4 * 4 + 2] += ak[k] * v.z;
            acc[j4 * 4 + 3] += ak[k] * v.w;
        }
    }
    unsigned short us[16];
#pragma unroll
    for (int j = 0; j < 16; ++j) us[j] = f2bf(acc[j]);
    unsigned short* dst = wb + (size_t)(b * COUT + o) * CIN + i0;
    *(uint4*)(dst) = *(const uint4*)(us);
    *(uint4*)(dst + 8) = *(const uint4*)(us + 8);
}

#define ASTR 264

// ---------------- K_Z: Z[b] = Wb[b] @ Ghat[b] ----------------
__global__ __launch_bounds__(256, 2) void k_z(const unsigned short* __restrict__ wb,
                                              const unsigned short* __restrict__ ghat,
                                              float* __restrict__ zout) {
    __shared__ unsigned short lds_a[128 * ASTR];
    int bid = blockIdx.x;
    int b = bid & 63;
    int tile = bid >> 6;               // 0..7
    int m0 = (tile & 3) * 128, n0 = (tile >> 2) * 128;
    int t = threadIdx.x;
    {
        int row = t >> 1, half = t & 1;
        const unsigned short* src = wb + (size_t)(b * COUT + m0 + row) * CIN + half * 128;
        unsigned short* dstrow = &lds_a[row * ASTR + half * 128];
#pragma unroll
        for (int j = 0; j < 16; ++j)
            *(uint4*)(dstrow + j * 8) = *(const uint4*)(src + j * 8);
    }
    __syncthreads();

    int lane = t & 63;
    int wid = t >> 6;
    int arow = lane & 15;
    int kq = lane >> 4;
    int col0 = n0 + wid * 32 + (lane & 15);
    int col1 = col0 + 16;
    const unsigned short* gb = ghat + (size_t)b * 256 * 256;

    f32x4 acc[8][2] = {};
#pragma unroll
    for (int kk = 0; kk < 8; ++kk) {
        bf16x8 b0 = *(const bf16x8*)(gb + (size_t)col0 * 256 + kk * 32 + kq * 8);
        bf16x8 b1 = *(const bf16x8*)(gb + (size_t)col1 * 256 + kk * 32 + kq * 8);
#pragma unroll
        for (int mf = 0; mf < 8; ++mf) {
            int row = mf * 16 + arow;
            bf16x8 a = *(const bf16x8*)&lds_a[row * ASTR + kk * 32 + kq * 8];
            acc[mf][0] = __builtin_amdgcn_mfma_f32_16x16x32_bf16(a, b0, acc[mf][0], 0, 0, 0);
            acc[mf][1] = __builtin_amdgcn_mfma_f32_16x16x32_bf16(a, b1, acc[mf][1], 0, 0, 0);
        }
    }
#pragma unroll
    for (int mf = 0; mf < 8; ++mf) {
#pragma unroll
        for (int r = 0; r < 4; ++r) {
            int row = m0 + mf * 16 + (lane >> 4) * 4 + r;
            size_t rb = ((size_t)b * COUT + row) * 256;
#pragma unroll
            for (int nf = 0; nf < 2; ++nf) {
                int col = n0 + wid * 32 + nf * 16 + (lane & 15);
                zout[rb + col] = acc[mf][nf][r];
            }
        }
    }
}

// ---------------- K_V: mu/rstd per (b,o) ----------------
__global__ __launch_bounds__(256) void k_v(const float* __restrict__ z,
                                           const unsigned short* __restrict__ wb,
                                           const float* __restrict__ pooled,
                                           float* __restrict__ mu,
                                           float* __restrict__ rstd) {
    int gid = blockIdx.x * 4 + (threadIdx.x >> 6);   // b*512 + o
    int lane = threadIdx.x & 63;
    int b = gid >> 9;
    const float* zr = z + (size_t)gid * 256;
    const unsigned short* wr = wb + (size_t)gid * 256;

    float4 zv = *(const float4*)(zr + lane * 4);
    ushort4 wu = *(const ushort4*)(wr + lane * 4);
    float w0 = bf2f(wu.x), w1 = bf2f(wu.y), w2 = bf2f(wu.z), w3 = bf2f(wu.w);
    float4 pv = *(const float4*)(pooled + b * CIN + lane * 4);

    float v = zv.x * w0 + zv.y * w1 + zv.z * w2 + zv.w * w3;
    float m = pv.x * w0 + pv.y * w1 + pv.z * w2 + pv.w * w3;
#pragma unroll
    for (int off = 1; off < 64; off <<= 1) {
        v += __shfl_xor(v, off);
        m += __shfl_xor(m, off);
    }
    if (lane == 0) {
        float var = v - m * m;
        mu[gid] = m;
        rstd[gid] = rsqrtf(var + 1e-5f);
    }
}

static __device__ __forceinline__ float gelu_t(float z) {
    float d = -1.5957691216f * z * (1.f + 0.044715f * z * z);
    return z * __builtin_amdgcn_rcpf(1.f + __expf(d));
}

// ---------------- K_MAIN14: DMA-ring 1x-B (main11) + LDS-bounce full-line stores (main9) ----
// grid = 256 (1 block/CU): xcd=bid&7; local=bid>>3: rh=local&1 (256-row half),
// sq=(local>>1)&1 (2048-col half), bq=local>>2; b=xcd+8*bq (gram writer's XCD).
// 512 thr = 8 waves x 32 rows; A[2][8] in VGPR. B: 3-slot x 16KB ring (32 cols/step),
// wave w DMAs chunks 2w,2w+1; __syncthreads-managed (m97/main11-proven).
// Epilogue: raw acc -> wave-private eps (stride 66: <=2-way banks); every 2 steps
// flush 32 rows x 64 cols via b64 reads -> LN+GELU -> global_store_dwordx4 where
// 8 lanes = 128B contiguous per row.
#define EPW 66
__global__ __launch_bounds__(512) void k_main14(const unsigned short* __restrict__ xF,
                                                const unsigned short* __restrict__ wb,
                                                const float* __restrict__ mu,
                                                const float* __restrict__ rstd,
                                                const float* __restrict__ gamma,
                                                const float* __restrict__ beta,
                                                float* __restrict__ out) {
    __shared__ unsigned short ring[3][8192];   // 48 KiB
    __shared__ float eps[8][32 * EPW];         // 67584 B
    __shared__ float gb_lds[2048];             // 8 KiB
    __shared__ float be_lds[2048];             // 8 KiB

    int bid = blockIdx.x;
    int xcd = bid & 7;
    int local = bid >> 3;
    int rh = local & 1;
    int sq = (local >> 1) & 1;
    int bq = local >> 2;
    int b = xcd + 8 * bq;

    int t = threadIdx.x, lane = t & 63, w = t >> 6;
    int lm = lane & 15, lk = lane >> 4;
    int row0 = rh * 256 + w * 32;
    int colbase = sq * 2048;

    // ---- gamma/beta half-slice -> LDS ----
    {
        float4 g4 = *(const float4*)(gamma + colbase + t * 4);
        float4 b4 = *(const float4*)(beta + colbase + t * 4);
        *(float4*)&gb_lds[t * 4] = g4;
        *(float4*)&be_lds[t * 4] = b4;
    }

    // ---- A frags: 32 rows/wave, direct from global (L2/L3-hot) ----
    bf16x8 A[2][8];
    const unsigned short* wbb = wb + (size_t)(b * COUT + row0 + lm) * CIN + lk * 8;
#pragma unroll
    for (int rf = 0; rf < 2; ++rf)
#pragma unroll
        for (int kk = 0; kk < 8; ++kk)
            A[rf][kk] = *(const bf16x8*)(wbb + (size_t)(rf * 16) * CIN + kk * 32);

    // ---- flush-role constants ----
    int r0 = lane >> 3;           // 0..7
    int c4 = (lane & 7) * 4;      // 0..28
    float muf[4], rsf[4];
#pragma unroll
    for (int j = 0; j < 4; ++j) {
        int row = b * COUT + row0 + r0 + 8 * j;
        muf[j] = mu[row];
        rsf[j] = rstd[row];
    }
    float* outb = out + (size_t)(b * COUT + row0) * S_ + colbase;
    float* epw = &eps[w][0];

    const unsigned short* xFq = xF + (size_t)b * S_ * CIN + (size_t)sq * 524288;

#define STAGE(st_, slot_)                                                          \
    {                                                                              \
        gl16(xFq + (size_t)((st_) * 16 + 2 * w) * 512 + lane * 8,                  \
             &ring[slot_][(2 * w) * 512]);                                         \
        gl16(xFq + (size_t)((st_) * 16 + 2 * w + 1) * 512 + lane * 8,              \
             &ring[slot_][(2 * w + 1) * 512]);                                     \
    }

    STAGE(0, 0)
    STAGE(1, 1)
    __syncthreads();   // gb_lds + DMA(0,1) landed

    for (int st = 0; st < 64; ++st) {
        if (st + 2 < 64) {
            int sp = st + 2, slot = sp - (sp / 3) * 3;
            STAGE(sp, slot)
        }

        const unsigned short* sl = &ring[st - (st / 3) * 3][0];
        f32x4 acc[2][2] = {};
#pragma unroll
        for (int cf = 0; cf < 2; ++cf) {
            bf16x8 Bf[8];
#pragma unroll
            for (int kb = 0; kb < 8; ++kb)
                Bf[kb] = *(const bf16x8*)(sl + (cf * 8 + kb) * 512 + lane * 8);
#pragma unroll
            for (int kb = 0; kb < 8; ++kb) {
                acc[0][cf] = __builtin_amdgcn_mfma_f32_16x16x32_bf16(A[0][kb], Bf[kb], acc[0][cf], 0, 0, 0);
                acc[1][cf] = __builtin_amdgcn_mfma_f32_16x16x32_bf16(A[1][kb], Bf[kb], acc[1][cf], 0, 0, 0);
            }
        }

        // ---- park raw acc into wave-private eps ----
#pragma unroll
        for (int cf = 0; cf < 2; ++cf)
#pragma unroll
            for (int rf = 0; rf < 2; ++rf)
#pragma unroll
                for (int rr = 0; rr < 4; ++rr)
                    epw[(rf * 16 + lk * 4 + rr) * EPW + (st & 1) * 32 + cf * 16 + lm] =
                        acc[rf][cf][rr];

        if (st & 1) {
            int fg = st >> 1;   // flush: cols colbase + fg*64 .. +63
#pragma unroll
            for (int j = 0; j < 4; ++j) {
                int rloc = r0 + 8 * j;
#pragma unroll
                for (int seg = 0; seg < 2; ++seg) {
                    int cl = seg * 32 + c4;
                    float2 lo = *(const float2*)&epw[rloc * EPW + cl];
                    float2 hi = *(const float2*)&epw[rloc * EPW + cl + 2];
                    float4 g4 = *(const float4*)&gb_lds[fg * 64 + cl];
                    float4 b4 = *(const float4*)&be_lds[fg * 64 + cl];
                    float4 o;
                    o.x = gelu_t((lo.x - muf[j]) * rsf[j] * g4.x + b4.x);
                    o.y = gelu_t((lo.y - muf[j]) * rsf[j] * g4.y + b4.y);
                    o.z = gelu_t((hi.x - muf[j]) * rsf[j] * g4.z + b4.z);
                    o.w = gelu_t((hi.y - muf[j]) * rsf[j] * g4.w + b4.w);
                    *(float4*)(outb + (size_t)rloc * S_ + fg * 64 + cl) = o;
                }
            }
        }
        __syncthreads();   // ring-slot reuse + DMA drain (compiler-managed waits)
    }
#undef STAGE
}

extern "C" void kernel_launch(void* const* d_in, const int* in_sizes, int n_in,
                              void* d_out, int out_size, void* d_ws, size_t ws_size,
                              hipStream_t stream) {
    const float* x      = (const float*)d_in[0];
    const float* w1     = (const float*)d_in[1];
    const float* w2     = (const float*)d_in[2];
    const float* b2     = (const float*)d_in[3];
    const float* conv_w = (const float*)d_in[4];
    // conv_b (d_in[5]) is annihilated by LayerNorm — unused.
    const float* gamma  = (const float*)d_in[6];
    const float* beta   = (const float*)d_in[7];
    float* out = (float*)d_out;

    float* pooled = (float*)d_ws;                                     // 64 KiB
    float* att    = (float*)((char*)d_ws + 65536);                    // 1 KiB
    unsigned short* wb   = (unsigned short*)((char*)d_ws + 262144);   // 16 MiB
    unsigned short* ghat = (unsigned short*)((char*)d_ws + 17039360); // 8 MiB
    float* mu   = (float*)((char*)d_ws + 25427968);                   // 128 KiB
    float* rstd = (float*)((char*)d_ws + 25559040);                   // 128 KiB
    float* ppart = (float*)((char*)d_ws + 25690112);                  // 256 KiB
    // xF: 128 MiB @ 32 MiB (ws_size >= 161.5 MiB proven — xF path ran in R4-R12)
    unsigned short* xF = (unsigned short*)((char*)d_ws + 33554432);

    // scratch inside d_out (537 MB): part (bf16, 33.5 MB) @0, zbuf 33.5 MB @64MB;
    // both dead before k_main14 rewrites d_out
    unsigned short* part = (unsigned short*)out;
    float* zbuf = (float*)((char*)d_out + 67108864);

    k_gram_part<<<256, 512, 0, stream>>>(x, part, ppart, xF);
    k_gred<<<B_, 256, 0, stream>>>(part, ppart, ghat, pooled);
    k_att<<<B_, 64, 0, stream>>>(pooled, w1, w2, b2, att);
    k_wb<<<B_ * 32, 256, 0, stream>>>(conv_w, att, wb);
    k_z<<<512, 256, 0, stream>>>(wb, ghat, zbuf);
    k_v<<<B_ * COUT / 4, 256, 0, stream>>>(zbuf, wb, pooled, mu, rstd);
    k_main14<<<256, 512, 0, stream>>>(xF, wb, mu, rstd, gamma, beta, out);
}

// Round 14
// 429.774 us; speedup vs baseline: 1.1560x; 1.0195x over previous
//
#include <hip/hip_runtime.h>
#include <hip/hip_bf16.h>

#define B_   64
#define CIN  256
#define COUT 512
#define S_   4096
#define HID  64
#define KEXP 4

typedef float f32x4 __attribute__((ext_vector_type(4)));
typedef short bf16x8 __attribute__((ext_vector_type(8)));

static __device__ __forceinline__ unsigned short f2bf(float f) {
    union { float f; unsigned u; } c; c.f = f;
    unsigned r = c.u + 0x7FFFu + ((c.u >> 16) & 1u);
    return (unsigned short)(r >> 16);
}
static __device__ __forceinline__ float bf2f(unsigned short u) {
    union { unsigned u; float f; } c; c.u = ((unsigned)u) << 16;
    return c.f;
}

// async global->LDS DMA, 16B per lane (HW: lds dest = uniform base + lane*16)
static __device__ __forceinline__ void gl16(const unsigned short* g, unsigned short* l) {
    __builtin_amdgcn_global_load_lds(
        (const __attribute__((address_space(1))) void*)g,
        (__attribute__((address_space(3))) void*)l,
        16, 0, 0);
}

// ---------------- K_GRAM_PART: partial Gram (bf16) + partial pooled + xF (frag-packed bf16) ----
#define GSTR 68   // shorts per LDS row (136B)
__global__ __launch_bounds__(512, 2) void k_gram_part(const float* __restrict__ x,
                                                      unsigned short* __restrict__ part,
                                                      float* __restrict__ ppart,
                                                      unsigned short* __restrict__ xF) {
    __shared__ unsigned short lds[256 * GSTR];   // 34816 B
    int bid = blockIdx.x;
    int b = bid & 63, sc = bid >> 6;
    int t = threadIdx.x, lane = t & 63, wv = t >> 6;
    int wr = wv >> 1, wc = wv & 1;               // wave tile: rows wr*64.., cols wc*128..
    const float* xb = x + (size_t)b * CIN * S_;
    unsigned short* xFb = xF + (size_t)b * S_ * CIN;

    f32x4 acc[4][8] = {};
    float psum[8] = {0.f, 0.f, 0.f, 0.f, 0.f, 0.f, 0.f, 0.f};

    for (int step = 0; step < 16; ++step) {
        int s0 = sc * 1024 + step * 64;
        __syncthreads();
#pragma unroll
        for (int p = 0; p < 8; ++p) {
            int i = t + p * 512;
            int row = i >> 4, f4 = i & 15;
            float4 v = *(const float4*)(xb + (size_t)row * S_ + s0 + f4 * 4);
            psum[p] += v.x + v.y + v.z + v.w;
            unsigned short u[4] = {f2bf(v.x), f2bf(v.y), f2bf(v.z), f2bf(v.w)};
            *(uint2*)&lds[row * GSTR + f4 * 4] = *(const uint2*)u;
        }
        __syncthreads();
        // ---- xF write: frag-packed, 1KB-contiguous per wave-chunk ----
        {
#pragma unroll
            for (int it = 0; it < 4; ++it) {
                int slot = t + it * 512;
                int chunk = slot >> 6;           // 0..31 = st_l*8 + kb
                int st_l = chunk >> 3, kb = chunk & 7;
                int l = slot & 63;
                unsigned short tmp[8];
#pragma unroll
                for (int j = 0; j < 8; ++j)
                    tmp[j] = lds[(kb * 32 + (l >> 4) * 8 + j) * GSTR + st_l * 16 + (l & 15)];
                *(uint4*)(xFb + ((size_t)((s0 >> 4) + st_l) * 8 + kb) * 512 + l * 8) = *(const uint4*)tmp;
            }
        }
        // ---- Gram MFMA ----
#pragma unroll
        for (int kk = 0; kk < 2; ++kk) {
            bf16x8 bfr[8];
#pragma unroll
            for (int nf = 0; nf < 8; ++nf)
                bfr[nf] = *(const bf16x8*)&lds[(wc * 128 + nf * 16 + (lane & 15)) * GSTR + kk * 32 + (lane >> 4) * 8];
#pragma unroll
            for (int mfi = 0; mfi < 4; ++mfi) {
                bf16x8 afr = *(const bf16x8*)&lds[(wr * 64 + mfi * 16 + (lane & 15)) * GSTR + kk * 32 + (lane >> 4) * 8];
#pragma unroll
                for (int nf = 0; nf < 8; ++nf)
                    acc[mfi][nf] = __builtin_amdgcn_mfma_f32_16x16x32_bf16(afr, bfr[nf], acc[mfi][nf], 0, 0, 0);
            }
        }
    }
#pragma unroll
    for (int p = 0; p < 8; ++p) {
        float s = psum[p];
        s += __shfl_xor(s, 1); s += __shfl_xor(s, 2);
        s += __shfl_xor(s, 4); s += __shfl_xor(s, 8);
        if ((t & 15) == 0) ppart[((size_t)sc * 64 + b) * 256 + ((t + p * 512) >> 4)] = s;
    }
    unsigned short* pb = part + ((size_t)sc * 64 + b) * 65536;
#pragma unroll
    for (int mfi = 0; mfi < 4; ++mfi) {
#pragma unroll
        for (int r = 0; r < 4; ++r) {
            int row = wr * 64 + mfi * 16 + (lane >> 4) * 4 + r;
#pragma unroll
            for (int nf = 0; nf < 8; ++nf)
                pb[row * 256 + wc * 128 + nf * 16 + (lane & 15)] = f2bf(acc[mfi][nf][r]);
        }
    }
}

// ---------------- K_GRED: reduce 4 bf16 partials -> ghat bf16, pooled ----------------
__global__ __launch_bounds__(256) void k_gred(const unsigned short* __restrict__ part,
                                              const float* __restrict__ ppart,
                                              unsigned short* __restrict__ ghat,
                                              float* __restrict__ pooled) {
    int b = blockIdx.x, t = threadIdx.x;
    const size_t bo = (size_t)b * 65536;
    const size_t scs = (size_t)64 * 65536;
    const float inv = 1.f / S_;
    for (int it = 0; it < 32; ++it) {
        size_t i = bo + (size_t)(it * 256 + t) * 8;
        union { uint4 v; unsigned short s[8]; } a0, a1, a2, a3, o;
        a0.v = *(const uint4*)(part + i);
        a1.v = *(const uint4*)(part + scs + i);
        a2.v = *(const uint4*)(part + 2 * scs + i);
        a3.v = *(const uint4*)(part + 3 * scs + i);
#pragma unroll
        for (int j = 0; j < 8; ++j)
            o.s[j] = f2bf((bf2f(a0.s[j]) + bf2f(a1.s[j]) + bf2f(a2.s[j]) + bf2f(a3.s[j])) * inv);
        *(uint4*)&ghat[i] = o.v;
    }
    float p = ppart[(size_t)b * 256 + t] + ppart[(size_t)(64 + b) * 256 + t]
            + ppart[(size_t)(128 + b) * 256 + t] + ppart[(size_t)(192 + b) * 256 + t];
    pooled[b * 256 + t] = p * inv;
}

// ---------------- K2: attention weights ----------------
__global__ __launch_bounds__(64) void k_att(const float* __restrict__ pooled,
                                            const float* __restrict__ w1,
                                            const float* __restrict__ w2,
                                            const float* __restrict__ b2,
                                            float* __restrict__ att_out) {
    int b = blockIdx.x, t = threadIdx.x;
    __shared__ float pl[CIN];
    __shared__ float hl[HID];
    __shared__ float satt[KEXP];
    for (int j = t; j < CIN; j += 64) pl[j] = pooled[b * CIN + j];
    __syncthreads();
    float acc = 0.f;
    const float* w1r = w1 + t * CIN;
#pragma unroll 4
    for (int c = 0; c < CIN; c += 4) {
        float4 w = *(const float4*)(w1r + c);
        acc += w.x * pl[c] + w.y * pl[c + 1] + w.z * pl[c + 2] + w.w * pl[c + 3];
    }
    hl[t] = fmaxf(acc, 0.f);
    __syncthreads();
    if (t < KEXP) {
        float a = 0.f;
        for (int j = 0; j < HID; ++j) a += hl[j] * w2[t * HID + j];
        satt[t] = (a + b2[t]) * (1.0f / 30.0f);
    }
    __syncthreads();
    if (t == 0) {
        float m = fmaxf(fmaxf(satt[0], satt[1]), fmaxf(satt[2], satt[3]));
        float e0 = expf(satt[0] - m), e1 = expf(satt[1] - m);
        float e2 = expf(satt[2] - m), e3 = expf(satt[3] - m);
        float inv = 1.f / (e0 + e1 + e2 + e3);
        att_out[b * KEXP + 0] = e0 * inv;
        att_out[b * KEXP + 1] = e1 * inv;
        att_out[b * KEXP + 2] = e2 * inv;
        att_out[b * KEXP + 3] = e3 * inv;
    }
}

// ---------------- K2b: Wb[b] = sum_k att[b,k] conv_w[k]  (bf16 to ws) ----------------
__global__ __launch_bounds__(256) void k_wb(const float* __restrict__ conv_w,
                                            const float* __restrict__ att,
                                            unsigned short* __restrict__ wb) {
    int bid = blockIdx.x;
    int b = bid >> 5, o0 = (bid & 31) * 16;
    int t = threadIdx.x;
    int o = o0 + (t >> 4);
    int i0 = (t & 15) * 16;
    float ak[KEXP];
#pragma unroll
    for (int k = 0; k < KEXP; ++k) ak[k] = att[b * KEXP + k];
    float acc[16];
#pragma unroll
    for (int j = 0; j < 16; ++j) acc[j] = 0.f;
#pragma unroll
    for (int k = 0; k < KEXP; ++k) {
        const float* src = conv_w + ((size_t)(k * COUT + o)) * CIN + i0;
#pragma unroll
        for (int j4 = 0; j4 < 4; ++j4) {
            float4 v = *(const float4*)(src + j4 * 4);
            acc[j4 * 4 + 0] += ak[k] * v.x;
            acc[j4 * 4 + 1] += ak[k] * v.y;
            acc[j4 * 4 + 2] += ak[k] * v.z;
            acc[j4 * 4 + 3] += ak[k] * v.w;
        }
    }
    unsigned short us[16];
#pragma unroll
    for (int j = 0; j < 16; ++j) us[j] = f2bf(acc[j]);
    unsigned short* dst = wb + (size_t)(b * COUT + o) * CIN + i0;
    *(uint4*)(dst) = *(const uint4*)(us);
    *(uint4*)(dst + 8) = *(const uint4*)(us + 8);
}

#define ASTR 264

// ---------------- K_Z: Z[b] = Wb[b] @ Ghat[b] ----------------
__global__ __launch_bounds__(256, 2) void k_z(const unsigned short* __restrict__ wb,
                                              const unsigned short* __restrict__ ghat,
                                              float* __restrict__ zout) {
    __shared__ unsigned short lds_a[128 * ASTR];
    int bid = blockIdx.x;
    int b = bid & 63;
    int tile = bid >> 6;               // 0..7
    int m0 = (tile & 3) * 128, n0 = (tile >> 2) * 128;
    int t = threadIdx.x;
    {
        int row = t >> 1, half = t & 1;
        const unsigned short* src = wb + (size_t)(b * COUT + m0 + row) * CIN + half * 128;
        unsigned short* dstrow = &lds_a[row * ASTR + half * 128];
#pragma unroll
        for (int j = 0; j < 16; ++j)
            *(uint4*)(dstrow + j * 8) = *(const uint4*)(src + j * 8);
    }
    __syncthreads();

    int lane = t & 63;
    int wid = t >> 6;
    int arow = lane & 15;
    int kq = lane >> 4;
    int col0 = n0 + wid * 32 + (lane & 15);
    int col1 = col0 + 16;
    const unsigned short* gb = ghat + (size_t)b * 256 * 256;

    f32x4 acc[8][2] = {};
#pragma unroll
    for (int kk = 0; kk < 8; ++kk) {
        bf16x8 b0 = *(const bf16x8*)(gb + (size_t)col0 * 256 + kk * 32 + kq * 8);
        bf16x8 b1 = *(const bf16x8*)(gb + (size_t)col1 * 256 + kk * 32 + kq * 8);
#pragma unroll
        for (int mf = 0; mf < 8; ++mf) {
            int row = mf * 16 + arow;
            bf16x8 a = *(const bf16x8*)&lds_a[row * ASTR + kk * 32 + kq * 8];
            acc[mf][0] = __builtin_amdgcn_mfma_f32_16x16x32_bf16(a, b0, acc[mf][0], 0, 0, 0);
            acc[mf][1] = __builtin_amdgcn_mfma_f32_16x16x32_bf16(a, b1, acc[mf][1], 0, 0, 0);
        }
    }
#pragma unroll
    for (int mf = 0; mf < 8; ++mf) {
#pragma unroll
        for (int r = 0; r < 4; ++r) {
            int row = m0 + mf * 16 + (lane >> 4) * 4 + r;
            size_t rb = ((size_t)b * COUT + row) * 256;
#pragma unroll
            for (int nf = 0; nf < 2; ++nf) {
                int col = n0 + wid * 32 + nf * 16 + (lane & 15);
                zout[rb + col] = acc[mf][nf][r];
            }
        }
    }
}

// ---------------- K_V: mu/rstd per (b,o) ----------------
__global__ __launch_bounds__(256) void k_v(const float* __restrict__ z,
                                           const unsigned short* __restrict__ wb,
                                           const float* __restrict__ pooled,
                                           float* __restrict__ mu,
                                           float* __restrict__ rstd) {
    int gid = blockIdx.x * 4 + (threadIdx.x >> 6);   // b*512 + o
    int lane = threadIdx.x & 63;
    int b = gid >> 9;
    const float* zr = z + (size_t)gid * 256;
    const unsigned short* wr = wb + (size_t)gid * 256;

    float4 zv = *(const float4*)(zr + lane * 4);
    ushort4 wu = *(const ushort4*)(wr + lane * 4);
    float w0 = bf2f(wu.x), w1 = bf2f(wu.y), w2 = bf2f(wu.z), w3 = bf2f(wu.w);
    float4 pv = *(const float4*)(pooled + b * CIN + lane * 4);

    float v = zv.x * w0 + zv.y * w1 + zv.z * w2 + zv.w * w3;
    float m = pv.x * w0 + pv.y * w1 + pv.z * w2 + pv.w * w3;
#pragma unroll
    for (int off = 1; off < 64; off <<= 1) {
        v += __shfl_xor(v, off);
        m += __shfl_xor(m, off);
    }
    if (lane == 0) {
        float var = v - m * m;
        mu[gid] = m;
        rstd[gid] = rsqrtf(var + 1e-5f);
    }
}

static __device__ __forceinline__ float gelu_t(float z) {
    float d = -1.5957691216f * z * (1.f + 0.044715f * z * z);
    return z * __builtin_amdgcn_rcpf(1.f + __expf(d));
}

// ---------------- K_MAIN15: main14's schedule at 2 blocks/CU ----------------
// grid = 512 (2 blocks/CU): xcd=bid&7; local=bid>>3: rh=local&1 (256-row half),
// sq=(local>>1)&3 (1024-col quarter), bq=local>>3; b=xcd+8*bq (gram writer's XCD).
// 512 thr = 8 waves x 32 rows; A[2][8] in VGPR. B: 4-slot x 8KB ring (16 cols/step,
// 64 steps), wave w DMAs chunk w; depth-3 prefetch, __syncthreads-managed.
// Epilogue: acc -> wave-private eps (stride 36: 16B-aligned, <=2-way banks); every
// 2 steps flush 32 rows x 32 cols -> LN+GELU -> float4 stores, 8 lanes = 128B/row.
// LDS = 32K ring + 36K eps + 8K gb = 76.6 KB -> 2 blocks/CU; VGPR<=128 ((512,4)).
#define EPW 36
__global__ __launch_bounds__(512, 4) void k_main15(const unsigned short* __restrict__ xF,
                                                   const unsigned short* __restrict__ wb,
                                                   const float* __restrict__ mu,
                                                   const float* __restrict__ rstd,
                                                   const float* __restrict__ gamma,
                                                   const float* __restrict__ beta,
                                                   float* __restrict__ out) {
    __shared__ unsigned short ring[4][4096];   // 32 KiB
    __shared__ float eps[8][32 * EPW];         // 36864 B
    __shared__ float gb_lds[1024];             // 4 KiB
    __shared__ float be_lds[1024];             // 4 KiB

    int bid = blockIdx.x;
    int xcd = bid & 7;
    int local = bid >> 3;
    int rh = local & 1;
    int sq = (local >> 1) & 3;
    int bq = local >> 3;
    int b = xcd + 8 * bq;

    int t = threadIdx.x, lane = t & 63, w = t >> 6;
    int lm = lane & 15, lk = lane >> 4;
    int row0 = rh * 256 + w * 32;
    int colbase = sq * 1024;

    // ---- gamma/beta quarter-slice -> LDS ----
    {
        float2 g2 = *(const float2*)(gamma + colbase + t * 2);
        float2 b2v = *(const float2*)(beta + colbase + t * 2);
        *(float2*)&gb_lds[t * 2] = g2;
        *(float2*)&be_lds[t * 2] = b2v;
    }

    // ---- A frags: 32 rows/wave, direct from global (L2/L3-hot) ----
    bf16x8 A[2][8];
    const unsigned short* wbb = wb + (size_t)(b * COUT + row0 + lm) * CIN + lk * 8;
#pragma unroll
    for (int rf = 0; rf < 2; ++rf)
#pragma unroll
        for (int kk = 0; kk < 8; ++kk)
            A[rf][kk] = *(const bf16x8*)(wbb + (size_t)(rf * 16) * CIN + kk * 32);

    // ---- flush-role constants: lane covers rows r0+8j (j<4), cols c4..c4+3 of 32 ----
    int r0 = lane >> 3;           // 0..7
    int c4 = (lane & 7) * 4;      // 0..28
    float muf[4], rsf[4];
#pragma unroll
    for (int j = 0; j < 4; ++j) {
        int row = b * COUT + row0 + r0 + 8 * j;
        muf[j] = mu[row];
        rsf[j] = rstd[row];
    }
    float* outb = out + (size_t)(b * COUT + row0) * S_ + colbase;
    float* epw = &eps[w][0];

    const unsigned short* xFq = xF + (size_t)b * S_ * CIN + (size_t)sq * 262144;

#define STAGE(st_, slot_)                                                          \
    gl16(xFq + (size_t)((st_) * 8 + w) * 512 + lane * 8, &ring[slot_][w * 512]);

    STAGE(0, 0)
    STAGE(1, 1)
    STAGE(2, 2)
    __syncthreads();   // gb_lds + DMA(0,1,2) landed

    for (int st = 0; st < 64; ++st) {
        if (st + 3 < 64) {
            int sp = st + 3;
            STAGE(sp, sp & 3)
        }

        const unsigned short* sl = &ring[st & 3][0];
        bf16x8 Bf[8];
#pragma unroll
        for (int kb = 0; kb < 8; ++kb)
            Bf[kb] = *(const bf16x8*)(sl + kb * 512 + lane * 8);

        f32x4 acc[2] = {};
#pragma unroll
        for (int kb = 0; kb < 8; ++kb) {
            acc[0] = __builtin_amdgcn_mfma_f32_16x16x32_bf16(A[0][kb], Bf[kb], acc[0], 0, 0, 0);
            acc[1] = __builtin_amdgcn_mfma_f32_16x16x32_bf16(A[1][kb], Bf[kb], acc[1], 0, 0, 0);
        }

        // ---- park raw acc into wave-private eps ----
#pragma unroll
        for (int rf = 0; rf < 2; ++rf)
#pragma unroll
            for (int rr = 0; rr < 4; ++rr)
                epw[(rf * 16 + lk * 4 + rr) * EPW + (st & 1) * 16 + lm] = acc[rf][rr];

        if (st & 1) {
            int fg = st >> 1;   // flush: cols colbase + fg*32 .. +31
#pragma unroll
            for (int j = 0; j < 4; ++j) {
                int rloc = r0 + 8 * j;
                float4 v = *(const float4*)&epw[rloc * EPW + c4];
                float4 g4 = *(const float4*)&gb_lds[fg * 32 + c4];
                float4 b4 = *(const float4*)&be_lds[fg * 32 + c4];
                float4 o;
                o.x = gelu_t((v.x - muf[j]) * rsf[j] * g4.x + b4.x);
                o.y = gelu_t((v.y - muf[j]) * rsf[j] * g4.y + b4.y);
                o.z = gelu_t((v.z - muf[j]) * rsf[j] * g4.z + b4.z);
                o.w = gelu_t((v.w - muf[j]) * rsf[j] * g4.w + b4.w);
                *(float4*)(outb + (size_t)rloc * S_ + fg * 32 + c4) = o;
            }
        }
        __syncthreads();   // ring-slot reuse + DMA drain; 2nd block/CU covers the stall
    }
#undef STAGE
}

extern "C" void kernel_launch(void* const* d_in, const int* in_sizes, int n_in,
                              void* d_out, int out_size, void* d_ws, size_t ws_size,
                              hipStream_t stream) {
    const float* x      = (const float*)d_in[0];
    const float* w1     = (const float*)d_in[1];
    const float* w2     = (const float*)d_in[2];
    const float* b2     = (const float*)d_in[3];
    const float* conv_w = (const float*)d_in[4];
    // conv_b (d_in[5]) is annihilated by LayerNorm — unused.
    const float* gamma  = (const float*)d_in[6];
    const float* beta   = (const float*)d_in[7];
    float* out = (float*)d_out;

    float* pooled = (float*)d_ws;                                     // 64 KiB
    float* att    = (float*)((char*)d_ws + 65536);                    // 1 KiB
    unsigned short* wb   = (unsigned short*)((char*)d_ws + 262144);   // 16 MiB
    unsigned short* ghat = (unsigned short*)((char*)d_ws + 17039360); // 8 MiB
    float* mu   = (float*)((char*)d_ws + 25427968);                   // 128 KiB
    float* rstd = (float*)((char*)d_ws + 25559040);                   // 128 KiB
    float* ppart = (float*)((char*)d_ws + 25690112);                  // 256 KiB
    // xF: 128 MiB @ 32 MiB (ws_size >= 161.5 MiB proven — xF path ran in R4-R13)
    unsigned short* xF = (unsigned short*)((char*)d_ws + 33554432);

    // scratch inside d_out (537 MB): part (bf16, 33.5 MB) @0, zbuf 33.5 MB @64MB;
    // both dead before k_main15 rewrites d_out
    unsigned short* part = (unsigned short*)out;
    float* zbuf = (float*)((char*)d_out + 67108864);

    k_gram_part<<<256, 512, 0, stream>>>(x, part, ppart, xF);
    k_gred<<<B_, 256, 0, stream>>>(part, ppart, ghat, pooled);
    k_att<<<B_, 64, 0, stream>>>(pooled, w1, w2, b2, att);
    k_wb<<<B_ * 32, 256, 0, stream>>>(conv_w, att, wb);
    k_z<<<512, 256, 0, stream>>>(wb, ghat, zbuf);
    k_v<<<B_ * COUT / 4, 256, 0, stream>>>(zbuf, wb, pooled, mu, rstd);
    k_main15<<<512, 512, 0, stream>>>(xF, wb, mu, rstd, gamma, beta, out);
}